// Round 9
// baseline (167.639 us; speedup 1.0000x reference)
//
#include <hip/hip_runtime.h>
#include <hip/hip_bf16.h>

// Problem constants (M is a static constant in the reference; N,E derived from in_sizes)
#define D 128
#define MSEG 10000
#define CB 256       // coarse buckets per direction (512 blocks -> full machine in build_csr)
#define CAP 4096     // LDS pairs capacity per bucket (expected ~1953, 2.1x headroom)
#define PB 2048      // pairs per scatter block
#define NSBP 256     // padded offset-table stride

typedef __attribute__((ext_vector_type(8))) __bf16 bf16x8;
typedef __attribute__((ext_vector_type(4))) float f32x4;

// SYSTEM MODEL (R7 measured): F~105us fixed harness fills + K kernels. Only K optimizable.
// R8 ALGEBRAIC FOLD (verified correct): out = relu( x@Wt + mean_row(mean_col(xb[row])[col])@Wfold + b )
//   with Wt=Wv@Wu_top, Wfold=Wv@We@Wu_bot -> gemm_v deleted, aggregate raw bf16(x).
// R8 lesson (repeat of R2): fusing aggN into 256-block csr dropped TLP 12x and LOST 5us.
// R9: fold + R4's verified high-TLP structure: 512-block dual-dir build_csr (dir0 fused
// aggM, dir1 CSR flush) + 12500-block agg_mean + final GEMM. 4 dispatches.

__device__ __forceinline__ int cbkt(int c, int M) { return (c * CB) / M; }
__device__ __forceinline__ int rbkt(int r, int N) { return (int)(((long long)r * CB) / N); }

#if __has_builtin(__builtin_amdgcn_global_load_lds)
typedef __attribute__((address_space(1))) const unsigned int gu32;
typedef __attribute__((address_space(3))) unsigned int lu32;
__device__ __forceinline__ void dma16(const void* g, void* l) {
    __builtin_amdgcn_global_load_lds((gu32*)g, (lu32*)l, 16, 0, 0);
}
#else
__device__ __forceinline__ void dma16(const void* g, void* l) {
    *(bf16x8*)l = *(const bf16x8*)g;
}
#endif

// ---------------- DISPATCH 1: convert [0,NCB) | Wprep (NCB) | grouping scatter (> NCB) -----
__global__ __launch_bounds__(256) void prep_scatter(
        const float* __restrict__ x, const float* __restrict__ Wv,
        const float* __restrict__ We, const float* __restrict__ Wu,
        __bf16* __restrict__ wp, __bf16* __restrict__ xb, int rows, int NCB,
        const int* __restrict__ row, const int* __restrict__ col, int n,
        int2* __restrict__ cbins, int2* __restrict__ rbins,
        int* __restrict__ tabc, int* __restrict__ tabr, int M, int N) {
    __shared__ __bf16 Ws[16 * 128 * 8];   // 32KB planes (scatter overlays stage+hist here)
    __shared__ __bf16 As[2][4 * 128 * 8]; // 16KB
    __shared__ int wsum4[4];
    int tid = threadIdx.x;

    if ((int)blockIdx.x < NCB) {
        // ======== convert branch: 128 rows of x -> bf16 xb
        int r0 = blockIdx.x * 128;
        #pragma unroll
        for (int it = 0; it < 8; ++it) {
            int g = it * 256 + tid;           // 0..2047 = 128 rows x 16 col-groups
            int r = r0 + (g >> 4), cg = g & 15;
            if (r < rows) {
                const float* Ap = x + (size_t)r * D + cg * 8;
                float4 f0 = *(const float4*)Ap;
                float4 f1 = *(const float4*)(Ap + 4);
                union { bf16x8 v; __bf16 e[8]; } u;
                u.e[0] = (__bf16)f0.x; u.e[1] = (__bf16)f0.y; u.e[2] = (__bf16)f0.z; u.e[3] = (__bf16)f0.w;
                u.e[4] = (__bf16)f1.x; u.e[5] = (__bf16)f1.y; u.e[6] = (__bf16)f1.z; u.e[7] = (__bf16)f1.w;
                *(bf16x8*)&xb[(size_t)r * D + cg * 8] = u.v;
            }
        }
        return;
    }

    if ((int)blockIdx.x > NCB) {
        // ======== scatter branch (R4 structure, verified)
        int2* stage = (int2*)Ws;                       // 16KB overlay
        int* hist = (int*)((char*)Ws + PB * 8);        // 257
        int* offA = hist + 257;                        // 257
        int* curA = offA + 257;                        // 257
        int jb = blockIdx.x - NCB - 1;
        int base = jb * PB;
        int cc[8], rr[8], kc[8], kr[8];
        #pragma unroll
        for (int u = 0; u < 8; ++u) {
            int i = base + u * 256 + tid;
            if (i < n) {
                cc[u] = col[i]; rr[u] = row[i];
                kc[u] = cbkt(cc[u], M); kr[u] = rbkt(rr[u], N);
            } else { cc[u] = 0; rr[u] = 0; kc[u] = 256; kr[u] = 256; }
        }
        int lane = tid & 63, wv = tid >> 6;
        #pragma unroll
        for (int dir = 0; dir < 2; ++dir) {
            for (int i2 = tid; i2 < 257; i2 += 256) hist[i2] = 0;
            __syncthreads();
            #pragma unroll
            for (int u = 0; u < 8; ++u) atomicAdd(&hist[dir ? kr[u] : kc[u]], 1);
            __syncthreads();
            // exclusive scan over 256 buckets (4 full waves)
            int a = hist[tid];
            int incl = a;
            #pragma unroll
            for (int o = 1; o < 64; o <<= 1) { int t = __shfl_up(incl, o, 64); if (lane >= o) incl += t; }
            if (lane == 63) wsum4[wv] = incl;
            __syncthreads();
            int wb = 0;
            for (int j = 0; j < wv; ++j) wb += wsum4[j];
            int ex = wb + incl - a;
            offA[tid] = ex; curA[tid] = ex;
            if (tid == 255) { offA[256] = ex + a; curA[256] = ex + a; }
            __syncthreads();
            // place into LDS stage, grouped by bucket
            #pragma unroll
            for (int u = 0; u < 8; ++u) {
                int k = dir ? kr[u] : kc[u];
                int p = atomicAdd(&curA[k], 1);
                stage[p] = dir ? make_int2(rr[u], cc[u]) : make_int2(cc[u], rr[u]);
            }
            __syncthreads();
            // offset-table write (transposed: row=bucket, col=block)
            int* tab = dir ? tabr : tabc;
            tab[tid * NSBP + jb] = offA[tid];
            if (tid == 0) tab[256 * NSBP + jb] = offA[256];
            // contiguous flush of the grouped run
            int2* bins = dir ? rbins : cbins;
            for (int k2 = tid; k2 < PB; k2 += 256) bins[base + k2] = stage[k2];
            __syncthreads();   // stage reused by next dir
        }
        return;
    }

    // ======== Wprep block (blockIdx == NCB): three chained 128^3 tile GEMMs (R8, verified).
    int w = tid >> 6, lane = tid & 63;
    int quad = lane >> 4, l15 = lane & 15;
    int mh = (w >> 1) * 64, nh = (w & 1) * 64;
    f32x4 acc[4][4];

    auto cvtPlanes = [&](const float* src) {       // f32 128x128 -> bf16 planes in Ws
        #pragma unroll
        for (int it = 0; it < 8; ++it) {
            int idx = it * 256 + tid;
            int pg = idx >> 7, c = idx & 127;
            union { bf16x8 v; __bf16 e[8]; } u;
            #pragma unroll
            for (int j = 0; j < 8; ++j) u.e[j] = (__bf16)src[(pg * 8 + j) * 128 + c];
            *(bf16x8*)&Ws[(size_t)idx * 8] = u.v;
        }
    };
    auto stA = [&](const float* Asrc, int t, int b) {
        int k0 = t * 32;
        #pragma unroll
        for (int h = 0; h < 2; ++h) {
            int i = h * 256 + tid;
            int q = i >> 7, r = i & 127;
            const float* Ap = Asrc + (size_t)r * D + k0 + q * 8;
            float4 f0 = *(const float4*)Ap;
            float4 f1 = *(const float4*)(Ap + 4);
            union { bf16x8 v; __bf16 e[8]; } u;
            u.e[0] = (__bf16)f0.x; u.e[1] = (__bf16)f0.y; u.e[2] = (__bf16)f0.z; u.e[3] = (__bf16)f0.w;
            u.e[4] = (__bf16)f1.x; u.e[5] = (__bf16)f1.y; u.e[6] = (__bf16)f1.z; u.e[7] = (__bf16)f1.w;
            *(bf16x8*)&As[b][i * 8] = u.v;
        }
    };
    auto tileGemm = [&](const float* Asrc) {       // acc = Asrc(f32) @ planes(Ws)
        f32x4 z = {0.f, 0.f, 0.f, 0.f};
        #pragma unroll
        for (int i = 0; i < 4; ++i)
            #pragma unroll
            for (int j = 0; j < 4; ++j) acc[i][j] = z;
        stA(Asrc, 0, 0);
        for (int t = 0; t < 4; ++t) {
            __syncthreads();
            if (t + 1 < 4) stA(Asrc, t + 1, (t + 1) & 1);
            int b = t & 1;
            bf16x8 af[4], bfr[4];
            #pragma unroll
            for (int mi = 0; mi < 4; ++mi)
                af[mi] = *(const bf16x8*)&As[b][(quad * 128 + mh + mi * 16 + l15) * 8];
            #pragma unroll
            for (int ni = 0; ni < 4; ++ni)
                bfr[ni] = *(const bf16x8*)&Ws[((t * 4 + quad) * 128 + nh + ni * 16 + l15) * 8];
            #pragma unroll
            for (int mi = 0; mi < 4; ++mi)
                #pragma unroll
                for (int ni = 0; ni < 4; ++ni)
                    acc[mi][ni] = __builtin_amdgcn_mfma_f32_16x16x32_bf16(af[mi], bfr[ni], acc[mi][ni], 0, 0, 0);
        }
        __syncthreads();                           // all reads of Ws/As done
    };
    auto wrLds = [&]() {                           // acc -> planes in Ws (overwrites)
        #pragma unroll
        for (int ni = 0; ni < 4; ++ni) {
            int colc = nh + ni * 16 + l15;
            #pragma unroll
            for (int mi = 0; mi < 4; ++mi)
                #pragma unroll
                for (int v = 0; v < 4; ++v) {
                    int rl = mh + mi * 16 + quad * 4 + v;
                    Ws[(size_t)(((rl >> 3) * 128 + colc) * 8) + (rl & 7)] = (__bf16)acc[mi][ni][v];
                }
        }
    };
    auto wrGlb = [&](int pbase) {                  // acc -> planes in wp[pbase..]
        #pragma unroll
        for (int ni = 0; ni < 4; ++ni) {
            int colc = nh + ni * 16 + l15;
            #pragma unroll
            for (int mi = 0; mi < 4; ++mi)
                #pragma unroll
                for (int v = 0; v < 4; ++v) {
                    int rl = mh + mi * 16 + quad * 4 + v;
                    wp[(size_t)(((pbase + (rl >> 3)) * 128 + colc) * 8) + (rl & 7)] = (__bf16)acc[mi][ni][v];
                }
        }
    };

    cvtPlanes(Wu + 128 * 128);         // Wu_bot planes
    __syncthreads();
    tileGemm(We);                      // acc = We @ Wu_bot
    wrLds();                           // Wc -> Ws planes
    __syncthreads();
    tileGemm(Wv);                      // acc = Wv @ Wc
    wrGlb(16);                         // Wfold -> wp planes 16..31
    cvtPlanes(Wu);                     // Wu_top planes
    __syncthreads();
    tileGemm(Wv);                      // acc = Wv @ Wu_top
    wrGlb(0);                          // Wt -> wp planes 0..15
}

// ---------------- DISPATCH 2: build CSR + fused aggM (512 blocks, both dirs) ---------------
// dir=0 (col-keyed): sort bucket pairs in LDS, gather-mean xb rows -> ef. Local positions.
// dir=1 (row-keyed): sort + flush roff/rlist (global base = sum of tab row).  [R4 verified]
__global__ __launch_bounds__(1024) void build_csr(
        const int2* __restrict__ cbins, const int2* __restrict__ rbins,
        const int* __restrict__ tabc, const int* __restrict__ tabr,
        int* __restrict__ roff, int* __restrict__ rlist,
        const __bf16* __restrict__ xb, __bf16* __restrict__ ef,
        int M, int N, int E_, int NSB) {
    __shared__ int hist[200];
    __shared__ int cur[200];
    __shared__ int sst[200];
    __shared__ int o0A[NSBP], cntA[NSBP], dstA[NSBP];
    __shared__ int2 sraw[CAP];            // 32KB raw bucket pairs
    __shared__ int sord[CAP];             // 16KB key-ordered payloads
    __shared__ int wsum[16];
    __shared__ int wsum4[4];
    __shared__ int sbaseS, bcntS;
    int b = blockIdx.x, tid = threadIdx.x;
    int dir = b >> 8, bb = b & (CB - 1);
    int tot = dir ? N : M;
    int lo = (bb * tot + CB - 1) / CB;    // first key in bucket
    int hi = ((bb + 1) * tot + CB - 1) / CB;
    int nb = hi - lo;                     // <= 196
    const int* tab = dir ? tabr : tabc;
    const int2* bins = dir ? rbins : cbins;
    int lane = tid & 63, wv = tid >> 6;

    // ---- per-source-block offsets/counts (tab rows bb, bb+1 — coalesced)
    int aa = 0, incl = 0;
    if (tid < 256) {
        int o0 = 0, c2 = 0;
        if (tid < NSB) {
            o0 = tab[bb * NSBP + tid];
            c2 = tab[(bb + 1) * NSBP + tid] - o0;
        }
        o0A[tid] = o0; cntA[tid] = c2;
        aa = c2; incl = c2;
        #pragma unroll
        for (int o = 1; o < 64; o <<= 1) { int t = __shfl_up(incl, o, 64); if (lane >= o) incl += t; }
        if (lane == 63) wsum4[wv] = incl;
    }
    for (int i = tid; i < nb; i += 1024) hist[i] = 0;
    __syncthreads();
    if (tid < 256) {
        int wb = 0;
        for (int j = 0; j < wv; ++j) wb += wsum4[j];
        dstA[tid] = wb + incl - aa;
    }
    if (tid < 64) {                       // wave 0: sbase = sum tab-row (= global CSR base)
        int s0 = 0, s1 = 0;
        for (int j = tid; j < 256; j += 64) { s0 += o0A[j]; s1 += cntA[j]; }
        #pragma unroll
        for (int o = 1; o < 64; o <<= 1) { s0 += __shfl_xor(s0, o, 64); s1 += __shfl_xor(s1, o, 64); }
        if (tid == 0) { sbaseS = s0; bcntS = s1; }
    }
    __syncthreads();
    int sbase = sbaseS;
    int bcnt = min(bcntS, CAP);
    int bstart = dir ? sbase : 0;         // dir0 works in local positions only

    // ---- gather this bucket's pairs from NSB grouped runs into sraw
    {
        int jb = tid >> 2, sub = tid & 3;
        if (jb < NSB) {
            int o0 = o0A[jb], c2 = cntA[jb], d0 = dstA[jb];
            for (int i = sub; i < c2; i += 4)
                if (d0 + i < CAP) sraw[d0 + i] = bins[(size_t)jb * PB + o0 + i];
        }
    }
    __syncthreads();
    // ---- histogram by key
    for (int k = tid; k < bcnt; k += 1024) atomicAdd(&hist[sraw[k].x - lo], 1);
    __syncthreads();
    // ---- block exclusive scan over hist[0..nb)
    int ka = (tid < nb) ? hist[tid] : 0;
    int kincl = ka;
    #pragma unroll
    for (int o = 1; o < 64; o <<= 1) { int t = __shfl_up(kincl, o, 64); if (lane >= o) kincl += t; }
    if (lane == 63) wsum[wv] = kincl;
    __syncthreads();
    int wb2 = 0;
    for (int j = 0; j < wv; ++j) wb2 += wsum[j];
    int ex = bstart + wb2 + kincl - ka;
    if (tid < nb) {
        if (dir) roff[lo + tid] = ex;
        sst[tid] = ex; cur[tid] = ex;
    }
    __syncthreads();
    // ---- place pass: sraw -> key-ordered sord
    for (int k = tid; k < bcnt; k += 1024) {
        int2 pp = sraw[k];
        int p = atomicAdd(&cur[pp.x - lo], 1);
        sord[p - bstart] = pp.y;
    }
    __syncthreads();
    if (dir) {
        // coalesced flush of row-CSR
        for (int i = tid; i < bcnt; i += 1024) rlist[bstart + i] = sord[i];
        if (bb == 0 && tid == 0) roff[N] = E_;
        return;
    }
    // ---- fused aggM: 16 waves stride over segments; wave = 4 entry-slots x 16 col-lanes
    int slot = lane >> 4, cg = lane & 15;
    for (int k = wv; k < nb; k += 16) {
        int s = sst[k], e = cur[k];       // local positions (bstart=0)
        int cnt = e - s;
        float acc8[8];
        #pragma unroll
        for (int j = 0; j < 8; ++j) acc8[j] = 0.f;
        int i = s;
        for (; i + 8 <= e; i += 8) {
            int g0 = sord[i + slot];
            int g1 = sord[i + 4 + slot];
            bf16x8 v0 = *(const bf16x8*)&xb[(size_t)g0 * D + cg * 8];
            bf16x8 v1 = *(const bf16x8*)&xb[(size_t)g1 * D + cg * 8];
            #pragma unroll
            for (int j = 0; j < 8; ++j) acc8[j] += (float)v0[j] + (float)v1[j];
        }
        for (; i < e; i += 4) {
            int ii = i + slot;
            if (ii < e) {
                int g = sord[ii];
                bf16x8 v = *(const bf16x8*)&xb[(size_t)g * D + cg * 8];
                #pragma unroll
                for (int j = 0; j < 8; ++j) acc8[j] += (float)v[j];
            }
        }
        #pragma unroll
        for (int j = 0; j < 8; ++j) {
            acc8[j] += __shfl_xor(acc8[j], 16, 64);
            acc8[j] += __shfl_xor(acc8[j], 32, 64);
        }
        if (slot == 0) {
            float inv = 1.f / (float)max(cnt, 1);
            union { bf16x8 v; __bf16 e[8]; } u;
            #pragma unroll
            for (int j = 0; j < 8; ++j) u.e[j] = (__bf16)(acc8[j] * inv);
            *(bf16x8*)&ef[(size_t)(lo + k) * D + cg * 8] = u.v;
        }
    }
}

// ---------------- DISPATCH 3: segment mean (full TLP): one wave = 4 slots x 16 lanes -------
__global__ __launch_bounds__(256) void agg_mean(const __bf16* __restrict__ src, const int* __restrict__ off,
                                                const int* __restrict__ list, __bf16* __restrict__ dst,
                                                int nseg) {
    int seg = blockIdx.x * 4 + (threadIdx.x >> 6);
    if (seg >= nseg) return;
    int lane = threadIdx.x & 63;
    int slot = lane >> 4, cg = lane & 15;
    int s = off[seg], e = off[seg + 1];
    int cnt = e - s;
    float acc[8];
    #pragma unroll
    for (int j = 0; j < 8; ++j) acc[j] = 0.f;

    int i = s;
    for (; i + 8 <= e; i += 8) {
        int r0 = list[i + slot];
        int r1 = list[i + 4 + slot];
        bf16x8 v0 = *(const bf16x8*)&src[(size_t)r0 * D + cg * 8];
        bf16x8 v1 = *(const bf16x8*)&src[(size_t)r1 * D + cg * 8];
        #pragma unroll
        for (int j = 0; j < 8; ++j) acc[j] += (float)v0[j] + (float)v1[j];
    }
    for (; i < e; i += 4) {
        int ii = i + slot;
        if (ii < e) {
            int r = list[ii];
            bf16x8 v = *(const bf16x8*)&src[(size_t)r * D + cg * 8];
            #pragma unroll
            for (int j = 0; j < 8; ++j) acc[j] += (float)v[j];
        }
    }
    #pragma unroll
    for (int j = 0; j < 8; ++j) {
        acc[j] += __shfl_xor(acc[j], 16, 64);
        acc[j] += __shfl_xor(acc[j], 32, 64);
    }
    if (slot == 0) {
        float inv = 1.f / (float)max(cnt, 1);
        union { bf16x8 v; __bf16 e[8]; } u;
        #pragma unroll
        for (int j = 0; j < 8; ++j) u.e[j] = (__bf16)(acc[j] * inv);
        *(bf16x8*)&dst[(size_t)seg * D + cg * 8] = u.v;
    }
}

// ---------------- DISPATCH 4: out = relu( [xb | a2] @ [Wt ; Wfold] + b ) -------------------
template<int NCHUNK, bool ABF16, bool FINAL>
__global__ __launch_bounds__(256) void gemm_mfma(const void* __restrict__ A0v,
                                                 const void* __restrict__ A1v,
                                                 const __bf16* __restrict__ Wp,
                                                 const float* __restrict__ bias,
                                                 void* __restrict__ Cv, int rows) {
    __shared__ __bf16 Ws[NCHUNK * 16 * 128 * 8];   // 64KB (NCHUNK=2)
    __shared__ __bf16 As[2][4 * 128 * 8];          // 2 x 8KB
    int tid = threadIdx.x;
    int w = tid >> 6, lane = tid & 63;
    int quad = lane >> 4, l15 = lane & 15;
    int r0 = blockIdx.x * 128;
    int mh = (w >> 1) * 64, nh = (w & 1) * 64;

    #pragma unroll
    for (int it = 0; it < NCHUNK * 8; ++it) {
        int idx = it * 256 + tid;
        dma16(Wp + (size_t)idx * 8, &Ws[(size_t)idx * 8]);
    }

    f32x4 acc[4][4];
    {
        f32x4 z = {0.f, 0.f, 0.f, 0.f};
        #pragma unroll
        for (int i = 0; i < 4; ++i)
            #pragma unroll
            for (int j = 0; j < 4; ++j) acc[i][j] = z;
    }

    auto stageA = [&](int t, int b) {
        int src = t >> 2;
        int k0 = (t & 3) * 32;
        #pragma unroll
        for (int h = 0; h < 2; ++h) {
            int i = h * 256 + tid;
            int q = i >> 7, r = i & 127;
            int rr = min(r0 + r, rows - 1);
            if (ABF16) {
                const __bf16* Ap = (const __bf16*)(src ? A1v : A0v) + (size_t)rr * D + k0 + q * 8;
                dma16(Ap, &As[b][i * 8]);
            } else {
                const float* Ap = (const float*)A0v + (size_t)rr * D + k0 + q * 8;
                float4 f0 = *(const float4*)Ap;
                float4 f1 = *(const float4*)(Ap + 4);
                union { bf16x8 v; __bf16 e[8]; } u;
                u.e[0] = (__bf16)f0.x; u.e[1] = (__bf16)f0.y; u.e[2] = (__bf16)f0.z; u.e[3] = (__bf16)f0.w;
                u.e[4] = (__bf16)f1.x; u.e[5] = (__bf16)f1.y; u.e[6] = (__bf16)f1.z; u.e[7] = (__bf16)f1.w;
                *(bf16x8*)&As[b][i * 8] = u.v;
            }
        }
    };

    stageA(0, 0);
    const int T = NCHUNK * 4;
    for (int t = 0; t < T; ++t) {
        __syncthreads();                          // drains DMA for chunk t (+ Ws on t=0)
        if (t + 1 < T) stageA(t + 1, (t + 1) & 1);
        int b = t & 1;
        bf16x8 af[4], bfr[4];
        #pragma unroll
        for (int mi = 0; mi < 4; ++mi)
            af[mi] = *(const bf16x8*)&As[b][(quad * 128 + mh + mi * 16 + l15) * 8];
        #pragma unroll
        for (int ni = 0; ni < 4; ++ni)
            bfr[ni] = *(const bf16x8*)&Ws[((t * 4 + quad) * 128 + nh + ni * 16 + l15) * 8];
        #pragma unroll
        for (int mi = 0; mi < 4; ++mi)
            #pragma unroll
            for (int ni = 0; ni < 4; ++ni)
                acc[mi][ni] = __builtin_amdgcn_mfma_f32_16x16x32_bf16(af[mi], bfr[ni], acc[mi][ni], 0, 0, 0);
    }

    // ---- epilogue: C/D layout col=lane&15, row=quad*4+reg
    __bf16* Cb = (__bf16*)Cv;
    float* Cf = (float*)Cv;
    #pragma unroll
    for (int ni = 0; ni < 4; ++ni) {
        int colc = nh + ni * 16 + l15;
        float bv = FINAL ? bias[colc] : 0.f;
        #pragma unroll
        for (int mi = 0; mi < 4; ++mi) {
            #pragma unroll
            for (int v = 0; v < 4; ++v) {
                int r = r0 + mh + mi * 16 + quad * 4 + v;
                if (r < rows) {
                    float val = acc[mi][ni][v];
                    if (FINAL) Cf[(size_t)r * D + colc] = fmaxf(val + bv, 0.f);
                    else       Cb[(size_t)r * D + colc] = (__bf16)val;
                }
            }
        }
    }
}

extern "C" void kernel_launch(void* const* d_in, const int* in_sizes, int n_in,
                              void* d_out, int out_size, void* d_ws, size_t ws_size,
                              hipStream_t stream) {
    const float* x  = (const float*)d_in[0];
    const int*   ei = (const int*)d_in[1];
    const float* Wv = (const float*)d_in[2];
    const float* We = (const float*)d_in[3];
    const float* Wu = (const float*)d_in[4];
    const float* bu = (const float*)d_in[5];
    float* out = (float*)d_out;

    const int N = in_sizes[0] / D;       // 50000
    const int E = in_sizes[1] / 2;       // 500000
    const int M = MSEG;                  // 10000 (static in reference)
    const int* row = ei;
    const int* col = ei + E;

    // workspace carve-out (256B aligned)
    char* p = (char*)d_ws;
    auto alloc = [&](size_t bytes) { char* q = p; p += (bytes + 255) & ~(size_t)255; return q; };
    __bf16* xb = (__bf16*)alloc((size_t)N * D * 2);       // 12.8MB  bf16(x)
    __bf16* ef = (__bf16*)alloc((size_t)M * D * 2);       // 2.56MB  mean_col(xb[row])
    __bf16* a2 = (__bf16*)alloc((size_t)N * D * 2);       // 12.8MB  mean_row(ef[col])
    __bf16* wp = (__bf16*)alloc((size_t)32 * 128 * 8 * 2);// 64KB [Wt|Wfold] planes
    int* roff  = (int*)alloc((size_t)(N + 1) * 4);
    int* rlist = (int*)alloc((size_t)E * 4);

    const int NSB = (E + PB - 1) / PB;   // 245 scatter blocks (<= NSBP)
    int2* cbins = (int2*)alloc((size_t)NSB * PB * 8);     // 4MB grouped runs
    int2* rbins = (int2*)alloc((size_t)NSB * PB * 8);     // 4MB
    int* tabc = (int*)alloc((size_t)257 * NSBP * 4);      // 263KB offset table
    int* tabr = (int*)alloc((size_t)257 * NSBP * 4);

    const int NCB = (N + 127) / 128;     // convert blocks (391)

    prep_scatter<<<NCB + 1 + NSB, 256, 0, stream>>>(x, Wv, We, Wu, wp, xb, N, NCB,
                                                    row, col, E, cbins, rbins, tabc, tabr, M, N);
    build_csr<<<2 * CB, 1024, 0, stream>>>(cbins, rbins, tabc, tabr, roff, rlist,
                                           xb, ef, M, N, E, NSB);
    agg_mean<<<(N + 3) / 4, 256, 0, stream>>>(ef, roff, rlist, a2, N);
    gemm_mfma<2, true, true><<<(N + 127) / 128, 256, 0, stream>>>(xb, a2, wp, bu, out, N);
}

// Round 10
// 151.776 us; speedup vs baseline: 1.1045x; 1.1045x over previous
//
#include <hip/hip_runtime.h>
#include <hip/hip_bf16.h>

// Problem constants (M is a static constant in the reference; N,E derived from in_sizes)
#define D 128
#define MSEG 10000
#define CB 256       // coarse buckets per direction (512 blocks -> full machine in build_csr)
#define CAP 4096     // LDS pairs capacity per bucket (expected ~1953, 2.1x headroom)
#define PB 2048      // pairs per scatter block
#define NSBP 256     // padded offset-table stride

typedef __attribute__((ext_vector_type(8))) __bf16 bf16x8;
typedef __attribute__((ext_vector_type(4))) float f32x4;

// SYSTEM MODEL (R7 measured): F~105us fixed harness fills + K kernels. Only K optimizable.
// R8 FOLD (verified): out = relu( x@Wt + mean_row(mean_col(xb[row])[col])@Wfold + b ),
//   Wt=Wv@Wu_top, Wfold=Wv@(We@Wu_bot). gemm_v deleted.
// R9 lesson: the 3-chained-GEMM Wprep in ONE block PINNED dispatch 1 (~18us serial on 1 CU)
//   — that, not csr TLP, was the R8/R9 regression. R10: split the chain across dispatches:
//   D1 weight block = Wt only (1 GEMM, hidden); D2 extra block = Wc->Wfold 2-chain
//   (hidden under 23us 512-block CSR work, reusing its LDS, 16-wave 32x32 layout).

__device__ __forceinline__ int cbkt(int c, int M) { return (c * CB) / M; }
__device__ __forceinline__ int rbkt(int r, int N) { return (int)(((long long)r * CB) / N); }

#if __has_builtin(__builtin_amdgcn_global_load_lds)
typedef __attribute__((address_space(1))) const unsigned int gu32;
typedef __attribute__((address_space(3))) unsigned int lu32;
__device__ __forceinline__ void dma16(const void* g, void* l) {
    __builtin_amdgcn_global_load_lds((gu32*)g, (lu32*)l, 16, 0, 0);
}
#else
__device__ __forceinline__ void dma16(const void* g, void* l) {
    *(bf16x8*)l = *(const bf16x8*)g;
}
#endif

// ---------------- DISPATCH 1: convert [0,NCB) | Wt block (NCB) | grouping scatter (> NCB) --
__global__ __launch_bounds__(256) void prep_scatter(
        const float* __restrict__ x, const float* __restrict__ Wv,
        const float* __restrict__ Wu,
        __bf16* __restrict__ wp, __bf16* __restrict__ xb, int rows, int NCB,
        const int* __restrict__ row, const int* __restrict__ col, int n,
        int2* __restrict__ cbins, int2* __restrict__ rbins,
        int* __restrict__ tabc, int* __restrict__ tabr, int M, int N) {
    __shared__ __bf16 Ws[16 * 128 * 8];   // 32KB planes (scatter overlays stage+hist here)
    __shared__ __bf16 As[2][4 * 128 * 8]; // 16KB
    __shared__ int wsum4[4];
    int tid = threadIdx.x;

    if ((int)blockIdx.x < NCB) {
        // ======== convert branch: 128 rows of x -> bf16 xb
        int r0 = blockIdx.x * 128;
        #pragma unroll
        for (int it = 0; it < 8; ++it) {
            int g = it * 256 + tid;           // 0..2047 = 128 rows x 16 col-groups
            int r = r0 + (g >> 4), cg = g & 15;
            if (r < rows) {
                const float* Ap = x + (size_t)r * D + cg * 8;
                float4 f0 = *(const float4*)Ap;
                float4 f1 = *(const float4*)(Ap + 4);
                union { bf16x8 v; __bf16 e[8]; } u;
                u.e[0] = (__bf16)f0.x; u.e[1] = (__bf16)f0.y; u.e[2] = (__bf16)f0.z; u.e[3] = (__bf16)f0.w;
                u.e[4] = (__bf16)f1.x; u.e[5] = (__bf16)f1.y; u.e[6] = (__bf16)f1.z; u.e[7] = (__bf16)f1.w;
                *(bf16x8*)&xb[(size_t)r * D + cg * 8] = u.v;
            }
        }
        return;
    }

    if ((int)blockIdx.x > NCB) {
        // ======== scatter branch (R4 structure, verified)
        int2* stage = (int2*)Ws;                       // 16KB overlay
        int* hist = (int*)((char*)Ws + PB * 8);        // 257
        int* offA = hist + 257;                        // 257
        int* curA = offA + 257;                        // 257
        int jb = blockIdx.x - NCB - 1;
        int base = jb * PB;
        int cc[8], rr[8], kc[8], kr[8];
        #pragma unroll
        for (int u = 0; u < 8; ++u) {
            int i = base + u * 256 + tid;
            if (i < n) {
                cc[u] = col[i]; rr[u] = row[i];
                kc[u] = cbkt(cc[u], M); kr[u] = rbkt(rr[u], N);
            } else { cc[u] = 0; rr[u] = 0; kc[u] = 256; kr[u] = 256; }
        }
        int lane = tid & 63, wv = tid >> 6;
        #pragma unroll
        for (int dir = 0; dir < 2; ++dir) {
            for (int i2 = tid; i2 < 257; i2 += 256) hist[i2] = 0;
            __syncthreads();
            #pragma unroll
            for (int u = 0; u < 8; ++u) atomicAdd(&hist[dir ? kr[u] : kc[u]], 1);
            __syncthreads();
            // exclusive scan over 256 buckets (4 full waves)
            int a = hist[tid];
            int incl = a;
            #pragma unroll
            for (int o = 1; o < 64; o <<= 1) { int t = __shfl_up(incl, o, 64); if (lane >= o) incl += t; }
            if (lane == 63) wsum4[wv] = incl;
            __syncthreads();
            int wb = 0;
            for (int j = 0; j < wv; ++j) wb += wsum4[j];
            int ex = wb + incl - a;
            offA[tid] = ex; curA[tid] = ex;
            if (tid == 255) { offA[256] = ex + a; curA[256] = ex + a; }
            __syncthreads();
            // place into LDS stage, grouped by bucket
            #pragma unroll
            for (int u = 0; u < 8; ++u) {
                int k = dir ? kr[u] : kc[u];
                int p = atomicAdd(&curA[k], 1);
                stage[p] = dir ? make_int2(rr[u], cc[u]) : make_int2(cc[u], rr[u]);
            }
            __syncthreads();
            // offset-table write (transposed: row=bucket, col=block)
            int* tab = dir ? tabr : tabc;
            tab[tid * NSBP + jb] = offA[tid];
            if (tid == 0) tab[256 * NSBP + jb] = offA[256];
            // contiguous flush of the grouped run
            int2* bins = dir ? rbins : cbins;
            for (int k2 = tid; k2 < PB; k2 += 256) bins[base + k2] = stage[k2];
            __syncthreads();   // stage reused by next dir
        }
        return;
    }

    // ======== Wt block (blockIdx == NCB): ONE tile GEMM: Wt = Wv @ Wu_top -> wp[0..15]
    int w = tid >> 6, lane = tid & 63;
    int quad = lane >> 4, l15 = lane & 15;
    int mh = (w >> 1) * 64, nh = (w & 1) * 64;
    f32x4 acc[4][4];
    // Wu_top f32 -> bf16 planes in Ws
    #pragma unroll
    for (int it = 0; it < 8; ++it) {
        int idx = it * 256 + tid;
        int pg = idx >> 7, c = idx & 127;
        union { bf16x8 v; __bf16 e[8]; } u;
        #pragma unroll
        for (int j = 0; j < 8; ++j) u.e[j] = (__bf16)Wu[(pg * 8 + j) * 128 + c];
        *(bf16x8*)&Ws[(size_t)idx * 8] = u.v;
    }
    {
        f32x4 z = {0.f, 0.f, 0.f, 0.f};
        #pragma unroll
        for (int i = 0; i < 4; ++i)
            #pragma unroll
            for (int j = 0; j < 4; ++j) acc[i][j] = z;
    }
    auto stA = [&](int t, int b) {
        int k0 = t * 32;
        #pragma unroll
        for (int h = 0; h < 2; ++h) {
            int i = h * 256 + tid;
            int q = i >> 7, r = i & 127;
            const float* Ap = Wv + (size_t)r * D + k0 + q * 8;
            float4 f0 = *(const float4*)Ap;
            float4 f1 = *(const float4*)(Ap + 4);
            union { bf16x8 v; __bf16 e[8]; } u;
            u.e[0] = (__bf16)f0.x; u.e[1] = (__bf16)f0.y; u.e[2] = (__bf16)f0.z; u.e[3] = (__bf16)f0.w;
            u.e[4] = (__bf16)f1.x; u.e[5] = (__bf16)f1.y; u.e[6] = (__bf16)f1.z; u.e[7] = (__bf16)f1.w;
            *(bf16x8*)&As[b][i * 8] = u.v;
        }
    };
    stA(0, 0);
    for (int t = 0; t < 4; ++t) {
        __syncthreads();
        if (t + 1 < 4) stA(t + 1, (t + 1) & 1);
        int b = t & 1;
        bf16x8 af[4], bfr[4];
        #pragma unroll
        for (int mi = 0; mi < 4; ++mi)
            af[mi] = *(const bf16x8*)&As[b][(quad * 128 + mh + mi * 16 + l15) * 8];
        #pragma unroll
        for (int ni = 0; ni < 4; ++ni)
            bfr[ni] = *(const bf16x8*)&Ws[((t * 4 + quad) * 128 + nh + ni * 16 + l15) * 8];
        #pragma unroll
        for (int mi = 0; mi < 4; ++mi)
            #pragma unroll
            for (int ni = 0; ni < 4; ++ni)
                acc[mi][ni] = __builtin_amdgcn_mfma_f32_16x16x32_bf16(af[mi], bfr[ni], acc[mi][ni], 0, 0, 0);
    }
    #pragma unroll
    for (int ni = 0; ni < 4; ++ni) {
        int colc = nh + ni * 16 + l15;
        #pragma unroll
        for (int mi = 0; mi < 4; ++mi)
            #pragma unroll
            for (int v = 0; v < 4; ++v) {
                int rl = mh + mi * 16 + quad * 4 + v;
                wp[(size_t)(((rl >> 3) * 128 + colc) * 8) + (rl & 7)] = (__bf16)acc[mi][ni][v];
            }
    }
}

// ---------------- DISPATCH 2: build CSR + fused aggM (512 blocks) | Wfold block (512) ------
// dir=0: sort bucket pairs in LDS, gather-mean xb rows -> ef. dir=1: flush roff/rlist.
// block 2*CB: Wfold = Wv @ (We @ Wu_bot) -> wp[16..31], 2-chain hidden under CSR width,
// reusing sraw/sord as plane/A-stage LDS, 16 waves x 32x32 output (acc[2][2], low VGPR).
__global__ __launch_bounds__(1024) void build_csr(
        const int2* __restrict__ cbins, const int2* __restrict__ rbins,
        const int* __restrict__ tabc, const int* __restrict__ tabr,
        int* __restrict__ roff, int* __restrict__ rlist,
        const __bf16* __restrict__ xb, __bf16* __restrict__ ef,
        const float* __restrict__ Wv, const float* __restrict__ We,
        const float* __restrict__ Wu, __bf16* __restrict__ wp,
        int M, int N, int E_, int NSB) {
    __shared__ int hist[200];
    __shared__ int cur[200];
    __shared__ int sst[200];
    __shared__ int o0A[NSBP], cntA[NSBP], dstA[NSBP];
    __shared__ int2 sraw[CAP];            // 32KB raw bucket pairs | Wfold: B planes
    __shared__ int sord[CAP];             // 16KB ordered payloads | Wfold: A double-buffer
    __shared__ int wsum[16];
    __shared__ int wsum4[4];
    __shared__ int sbaseS, bcntS;
    int b = blockIdx.x, tid = threadIdx.x;
    int lane = tid & 63, wv = tid >> 6;

    if (b == 2 * CB) {
        // ======== Wfold block: acc = We@Wu_bot -> planes; acc2 = Wv@planes -> wp[16..31]
        __bf16* WsL = (__bf16*)sraw;      // 16 planes (32KB)
        __bf16* AsL = (__bf16*)sord;      // 2 x 4096 bf16 (16KB)
        int quad = lane >> 4, l15 = lane & 15;
        int w16 = tid >> 6;               // 0..15
        int mh = (w16 >> 2) * 32, nh = (w16 & 3) * 32;
        f32x4 acc[2][2];
        auto cvtP = [&](const float* src) {   // f32 128x128 -> planes in WsL
            for (int it = tid; it < 2048; it += 1024) {
                int pg = it >> 7, c = it & 127;
                union { bf16x8 v; __bf16 e[8]; } u;
                #pragma unroll
                for (int j = 0; j < 8; ++j) u.e[j] = (__bf16)src[(pg * 8 + j) * 128 + c];
                *(bf16x8*)&WsL[(size_t)it * 8] = u.v;
            }
        };
        auto stA = [&](const float* Asrc, int t, int b2) {
            if (tid < 512) {
                int k0 = t * 32;
                int q = tid >> 7, r = tid & 127;
                const float* Ap = Asrc + (size_t)r * D + k0 + q * 8;
                float4 f0 = *(const float4*)Ap;
                float4 f1 = *(const float4*)(Ap + 4);
                union { bf16x8 v; __bf16 e[8]; } u;
                u.e[0] = (__bf16)f0.x; u.e[1] = (__bf16)f0.y; u.e[2] = (__bf16)f0.z; u.e[3] = (__bf16)f0.w;
                u.e[4] = (__bf16)f1.x; u.e[5] = (__bf16)f1.y; u.e[6] = (__bf16)f1.z; u.e[7] = (__bf16)f1.w;
                *(bf16x8*)&AsL[(size_t)(b2 * 4096 + tid * 8)] = u.v;
            }
        };
        auto tg = [&](const float* Asrc) {     // acc = Asrc(f32) @ planes(WsL), 16 waves
            f32x4 z = {0.f, 0.f, 0.f, 0.f};
            #pragma unroll
            for (int i = 0; i < 2; ++i)
                #pragma unroll
                for (int j = 0; j < 2; ++j) acc[i][j] = z;
            stA(Asrc, 0, 0);
            for (int t = 0; t < 4; ++t) {
                __syncthreads();
                if (t + 1 < 4) stA(Asrc, t + 1, (t + 1) & 1);
                int b2 = t & 1;
                bf16x8 af[2], bfr[2];
                #pragma unroll
                for (int mi = 0; mi < 2; ++mi)
                    af[mi] = *(const bf16x8*)&AsL[(size_t)(b2 * 4096 + (quad * 128 + mh + mi * 16 + l15) * 8)];
                #pragma unroll
                for (int ni = 0; ni < 2; ++ni)
                    bfr[ni] = *(const bf16x8*)&WsL[((t * 4 + quad) * 128 + nh + ni * 16 + l15) * 8];
                #pragma unroll
                for (int mi = 0; mi < 2; ++mi)
                    #pragma unroll
                    for (int ni = 0; ni < 2; ++ni)
                        acc[mi][ni] = __builtin_amdgcn_mfma_f32_16x16x32_bf16(af[mi], bfr[ni], acc[mi][ni], 0, 0, 0);
            }
            __syncthreads();               // all reads of WsL/AsL done
        };

        cvtP(Wu + 128 * 128);              // Wu_bot planes
        __syncthreads();
        tg(We);                            // acc = We @ Wu_bot
        // acc -> Wc planes in WsL
        #pragma unroll
        for (int ni = 0; ni < 2; ++ni) {
            int colc = nh + ni * 16 + l15;
            #pragma unroll
            for (int mi = 0; mi < 2; ++mi)
                #pragma unroll
                for (int v = 0; v < 4; ++v) {
                    int rl = mh + mi * 16 + quad * 4 + v;
                    WsL[(size_t)(((rl >> 3) * 128 + colc) * 8) + (rl & 7)] = (__bf16)acc[mi][ni][v];
                }
        }
        __syncthreads();
        tg(Wv);                            // acc = Wv @ Wc
        #pragma unroll
        for (int ni = 0; ni < 2; ++ni) {
            int colc = nh + ni * 16 + l15;
            #pragma unroll
            for (int mi = 0; mi < 2; ++mi)
                #pragma unroll
                for (int v = 0; v < 4; ++v) {
                    int rl = mh + mi * 16 + quad * 4 + v;
                    wp[(size_t)(((16 + (rl >> 3)) * 128 + colc) * 8) + (rl & 7)] = (__bf16)acc[mi][ni][v];
                }
        }
        return;
    }

    int dir = b >> 8, bb = b & (CB - 1);
    int tot = dir ? N : M;
    int lo = (bb * tot + CB - 1) / CB;    // first key in bucket
    int hi = ((bb + 1) * tot + CB - 1) / CB;
    int nb = hi - lo;                     // <= 196
    const int* tab = dir ? tabr : tabc;
    const int2* bins = dir ? rbins : cbins;

    // ---- per-source-block offsets/counts (tab rows bb, bb+1 — coalesced)
    int aa = 0, incl = 0;
    if (tid < 256) {
        int o0 = 0, c2 = 0;
        if (tid < NSB) {
            o0 = tab[bb * NSBP + tid];
            c2 = tab[(bb + 1) * NSBP + tid] - o0;
        }
        o0A[tid] = o0; cntA[tid] = c2;
        aa = c2; incl = c2;
        #pragma unroll
        for (int o = 1; o < 64; o <<= 1) { int t = __shfl_up(incl, o, 64); if (lane >= o) incl += t; }
        if (lane == 63) wsum4[wv] = incl;
    }
    for (int i = tid; i < nb; i += 1024) hist[i] = 0;
    __syncthreads();
    if (tid < 256) {
        int wb = 0;
        for (int j = 0; j < wv; ++j) wb += wsum4[j];
        dstA[tid] = wb + incl - aa;
    }
    if (tid < 64) {                       // wave 0: sbase = sum tab-row (= global CSR base)
        int s0 = 0, s1 = 0;
        for (int j = tid; j < 256; j += 64) { s0 += o0A[j]; s1 += cntA[j]; }
        #pragma unroll
        for (int o = 1; o < 64; o <<= 1) { s0 += __shfl_xor(s0, o, 64); s1 += __shfl_xor(s1, o, 64); }
        if (tid == 0) { sbaseS = s0; bcntS = s1; }
    }
    __syncthreads();
    int sbase = sbaseS;
    int bcnt = min(bcntS, CAP);
    int bstart = dir ? sbase : 0;         // dir0 works in local positions only

    // ---- gather this bucket's pairs from NSB grouped runs into sraw
    {
        int jb = tid >> 2, sub = tid & 3;
        if (jb < NSB) {
            int o0 = o0A[jb], c2 = cntA[jb], d0 = dstA[jb];
            for (int i = sub; i < c2; i += 4)
                if (d0 + i < CAP) sraw[d0 + i] = bins[(size_t)jb * PB + o0 + i];
        }
    }
    __syncthreads();
    // ---- histogram by key
    for (int k = tid; k < bcnt; k += 1024) atomicAdd(&hist[sraw[k].x - lo], 1);
    __syncthreads();
    // ---- block exclusive scan over hist[0..nb)
    int ka = (tid < nb) ? hist[tid] : 0;
    int kincl = ka;
    #pragma unroll
    for (int o = 1; o < 64; o <<= 1) { int t = __shfl_up(kincl, o, 64); if (lane >= o) kincl += t; }
    if (lane == 63) wsum[wv] = kincl;
    __syncthreads();
    int wb2 = 0;
    for (int j = 0; j < wv; ++j) wb2 += wsum[j];
    int ex = bstart + wb2 + kincl - ka;
    if (tid < nb) {
        if (dir) roff[lo + tid] = ex;
        sst[tid] = ex; cur[tid] = ex;
    }
    __syncthreads();
    // ---- place pass: sraw -> key-ordered sord
    for (int k = tid; k < bcnt; k += 1024) {
        int2 pp = sraw[k];
        int p = atomicAdd(&cur[pp.x - lo], 1);
        sord[p - bstart] = pp.y;
    }
    __syncthreads();
    if (dir) {
        // coalesced flush of row-CSR
        for (int i = tid; i < bcnt; i += 1024) rlist[bstart + i] = sord[i];
        if (bb == 0 && tid == 0) roff[N] = E_;
        return;
    }
    // ---- fused aggM: 16 waves stride over segments; wave = 4 entry-slots x 16 col-lanes
    int slot = lane >> 4, cg = lane & 15;
    for (int k = wv; k < nb; k += 16) {
        int s = sst[k], e = cur[k];       // local positions (bstart=0)
        int cnt = e - s;
        float acc8[8];
        #pragma unroll
        for (int j = 0; j < 8; ++j) acc8[j] = 0.f;
        int i = s;
        for (; i + 8 <= e; i += 8) {
            int g0 = sord[i + slot];
            int g1 = sord[i + 4 + slot];
            bf16x8 v0 = *(const bf16x8*)&xb[(size_t)g0 * D + cg * 8];
            bf16x8 v1 = *(const bf16x8*)&xb[(size_t)g1 * D + cg * 8];
            #pragma unroll
            for (int j = 0; j < 8; ++j) acc8[j] += (float)v0[j] + (float)v1[j];
        }
        for (; i < e; i += 4) {
            int ii = i + slot;
            if (ii < e) {
                int g = sord[ii];
                bf16x8 v = *(const bf16x8*)&xb[(size_t)g * D + cg * 8];
                #pragma unroll
                for (int j = 0; j < 8; ++j) acc8[j] += (float)v[j];
            }
        }
        #pragma unroll
        for (int j = 0; j < 8; ++j) {
            acc8[j] += __shfl_xor(acc8[j], 16, 64);
            acc8[j] += __shfl_xor(acc8[j], 32, 64);
        }
        if (slot == 0) {
            float inv = 1.f / (float)max(cnt, 1);
            union { bf16x8 v; __bf16 e[8]; } u;
            #pragma unroll
            for (int j = 0; j < 8; ++j) u.e[j] = (__bf16)(acc8[j] * inv);
            *(bf16x8*)&ef[(size_t)(lo + k) * D + cg * 8] = u.v;
        }
    }
}

// ---------------- DISPATCH 3: segment mean (full TLP): one wave = 4 slots x 16 lanes -------
__global__ __launch_bounds__(256) void agg_mean(const __bf16* __restrict__ src, const int* __restrict__ off,
                                                const int* __restrict__ list, __bf16* __restrict__ dst,
                                                int nseg) {
    int seg = blockIdx.x * 4 + (threadIdx.x >> 6);
    if (seg >= nseg) return;
    int lane = threadIdx.x & 63;
    int slot = lane >> 4, cg = lane & 15;
    int s = off[seg], e = off[seg + 1];
    int cnt = e - s;
    float acc[8];
    #pragma unroll
    for (int j = 0; j < 8; ++j) acc[j] = 0.f;

    int i = s;
    for (; i + 8 <= e; i += 8) {
        int r0 = list[i + slot];
        int r1 = list[i + 4 + slot];
        bf16x8 v0 = *(const bf16x8*)&src[(size_t)r0 * D + cg * 8];
        bf16x8 v1 = *(const bf16x8*)&src[(size_t)r1 * D + cg * 8];
        #pragma unroll
        for (int j = 0; j < 8; ++j) acc[j] += (float)v0[j] + (float)v1[j];
    }
    for (; i < e; i += 4) {
        int ii = i + slot;
        if (ii < e) {
            int r = list[ii];
            bf16x8 v = *(const bf16x8*)&src[(size_t)r * D + cg * 8];
            #pragma unroll
            for (int j = 0; j < 8; ++j) acc[j] += (float)v[j];
        }
    }
    #pragma unroll
    for (int j = 0; j < 8; ++j) {
        acc[j] += __shfl_xor(acc[j], 16, 64);
        acc[j] += __shfl_xor(acc[j], 32, 64);
    }
    if (slot == 0) {
        float inv = 1.f / (float)max(cnt, 1);
        union { bf16x8 v; __bf16 e[8]; } u;
        #pragma unroll
        for (int j = 0; j < 8; ++j) u.e[j] = (__bf16)(acc[j] * inv);
        *(bf16x8*)&dst[(size_t)seg * D + cg * 8] = u.v;
    }
}

// ---------------- DISPATCH 4: out = relu( [xb | a2] @ [Wt ; Wfold] + b ) -------------------
template<int NCHUNK, bool ABF16, bool FINAL>
__global__ __launch_bounds__(256) void gemm_mfma(const void* __restrict__ A0v,
                                                 const void* __restrict__ A1v,
                                                 const __bf16* __restrict__ Wp,
                                                 const float* __restrict__ bias,
                                                 void* __restrict__ Cv, int rows) {
    __shared__ __bf16 Ws[NCHUNK * 16 * 128 * 8];   // 64KB (NCHUNK=2)
    __shared__ __bf16 As[2][4 * 128 * 8];          // 2 x 8KB
    int tid = threadIdx.x;
    int w = tid >> 6, lane = tid & 63;
    int quad = lane >> 4, l15 = lane & 15;
    int r0 = blockIdx.x * 128;
    int mh = (w >> 1) * 64, nh = (w & 1) * 64;

    #pragma unroll
    for (int it = 0; it < NCHUNK * 8; ++it) {
        int idx = it * 256 + tid;
        dma16(Wp + (size_t)idx * 8, &Ws[(size_t)idx * 8]);
    }

    f32x4 acc[4][4];
    {
        f32x4 z = {0.f, 0.f, 0.f, 0.f};
        #pragma unroll
        for (int i = 0; i < 4; ++i)
            #pragma unroll
            for (int j = 0; j < 4; ++j) acc[i][j] = z;
    }

    auto stageA = [&](int t, int b) {
        int src = t >> 2;
        int k0 = (t & 3) * 32;
        #pragma unroll
        for (int h = 0; h < 2; ++h) {
            int i = h * 256 + tid;
            int q = i >> 7, r = i & 127;
            int rr = min(r0 + r, rows - 1);
            if (ABF16) {
                const __bf16* Ap = (const __bf16*)(src ? A1v : A0v) + (size_t)rr * D + k0 + q * 8;
                dma16(Ap, &As[b][i * 8]);
            } else {
                const float* Ap = (const float*)A0v + (size_t)rr * D + k0 + q * 8;
                float4 f0 = *(const float4*)Ap;
                float4 f1 = *(const float4*)(Ap + 4);
                union { bf16x8 v; __bf16 e[8]; } u;
                u.e[0] = (__bf16)f0.x; u.e[1] = (__bf16)f0.y; u.e[2] = (__bf16)f0.z; u.e[3] = (__bf16)f0.w;
                u.e[4] = (__bf16)f1.x; u.e[5] = (__bf16)f1.y; u.e[6] = (__bf16)f1.z; u.e[7] = (__bf16)f1.w;
                *(bf16x8*)&As[b][i * 8] = u.v;
            }
        }
    };

    stageA(0, 0);
    const int T = NCHUNK * 4;
    for (int t = 0; t < T; ++t) {
        __syncthreads();                          // drains DMA for chunk t (+ Ws on t=0)
        if (t + 1 < T) stageA(t + 1, (t + 1) & 1);
        int b = t & 1;
        bf16x8 af[4], bfr[4];
        #pragma unroll
        for (int mi = 0; mi < 4; ++mi)
            af[mi] = *(const bf16x8*)&As[b][(quad * 128 + mh + mi * 16 + l15) * 8];
        #pragma unroll
        for (int ni = 0; ni < 4; ++ni)
            bfr[ni] = *(const bf16x8*)&Ws[((t * 4 + quad) * 128 + nh + ni * 16 + l15) * 8];
        #pragma unroll
        for (int mi = 0; mi < 4; ++mi)
            #pragma unroll
            for (int ni = 0; ni < 4; ++ni)
                acc[mi][ni] = __builtin_amdgcn_mfma_f32_16x16x32_bf16(af[mi], bfr[ni], acc[mi][ni], 0, 0, 0);
    }

    // ---- epilogue: C/D layout col=lane&15, row=quad*4+reg
    __bf16* Cb = (__bf16*)Cv;
    float* Cf = (float*)Cv;
    #pragma unroll
    for (int ni = 0; ni < 4; ++ni) {
        int colc = nh + ni * 16 + l15;
        float bv = FINAL ? bias[colc] : 0.f;
        #pragma unroll
        for (int mi = 0; mi < 4; ++mi) {
            #pragma unroll
            for (int v = 0; v < 4; ++v) {
                int r = r0 + mh + mi * 16 + quad * 4 + v;
                if (r < rows) {
                    float val = acc[mi][ni][v];
                    if (FINAL) Cf[(size_t)r * D + colc] = fmaxf(val + bv, 0.f);
                    else       Cb[(size_t)r * D + colc] = (__bf16)val;
                }
            }
        }
    }
}

extern "C" void kernel_launch(void* const* d_in, const int* in_sizes, int n_in,
                              void* d_out, int out_size, void* d_ws, size_t ws_size,
                              hipStream_t stream) {
    const float* x  = (const float*)d_in[0];
    const int*   ei = (const int*)d_in[1];
    const float* Wv = (const float*)d_in[2];
    const float* We = (const float*)d_in[3];
    const float* Wu = (const float*)d_in[4];
    const float* bu = (const float*)d_in[5];
    float* out = (float*)d_out;

    const int N = in_sizes[0] / D;       // 50000
    const int E = in_sizes[1] / 2;       // 500000
    const int M = MSEG;                  // 10000 (static in reference)
    const int* row = ei;
    const int* col = ei + E;

    // workspace carve-out (256B aligned)
    char* p = (char*)d_ws;
    auto alloc = [&](size_t bytes) { char* q = p; p += (bytes + 255) & ~(size_t)255; return q; };
    __bf16* xb = (__bf16*)alloc((size_t)N * D * 2);       // 12.8MB  bf16(x)
    __bf16* ef = (__bf16*)alloc((size_t)M * D * 2);       // 2.56MB  mean_col(xb[row])
    __bf16* a2 = (__bf16*)alloc((size_t)N * D * 2);       // 12.8MB  mean_row(ef[col])
    __bf16* wp = (__bf16*)alloc((size_t)32 * 128 * 8 * 2);// 64KB [Wt|Wfold] planes
    int* roff  = (int*)alloc((size_t)(N + 1) * 4);
    int* rlist = (int*)alloc((size_t)E * 4);

    const int NSB = (E + PB - 1) / PB;   // 245 scatter blocks (<= NSBP)
    int2* cbins = (int2*)alloc((size_t)NSB * PB * 8);     // 4MB grouped runs
    int2* rbins = (int2*)alloc((size_t)NSB * PB * 8);     // 4MB
    int* tabc = (int*)alloc((size_t)257 * NSBP * 4);      // 263KB offset table
    int* tabr = (int*)alloc((size_t)257 * NSBP * 4);

    const int NCB = (N + 127) / 128;     // convert blocks (391)

    prep_scatter<<<NCB + 1 + NSB, 256, 0, stream>>>(x, Wv, Wu, wp, xb, N, NCB,
                                                    row, col, E, cbins, rbins, tabc, tabr, M, N);
    build_csr<<<2 * CB + 1, 1024, 0, stream>>>(cbins, rbins, tabc, tabr, roff, rlist,
                                               xb, ef, Wv, We, Wu, wp, M, N, E, NSB);
    agg_mean<<<(N + 3) / 4, 256, 0, stream>>>(ef, roff, rlist, a2, N);
    gemm_mfma<2, true, true><<<(N + 127) / 128, 256, 0, stream>>>(xb, a2, wp, bu, out, N);
}